// Round 11
// baseline (1476.958 us; speedup 1.0000x reference)
//
#include <hip/hip_runtime.h>
#include <hip/hip_bf16.h>

#define DEV __device__ __forceinline__

constexpr int BB  = 128;   // batch
constexpr int TT  = 512;   // seq len
constexpr int HH  = 128;   // concat hidden
constexpr int H2  = 64;    // per-direction hidden
constexpr int GM  = 512;   // 4*HH (mve gates)

constexpr float L2E = 1.4426950408889634f;
constexpr float K2  = 2.0f * L2E;

typedef __attribute__((ext_vector_type(8))) short bf16x8;
typedef __attribute__((ext_vector_type(4))) float f32x4;

#define MFMA16(a_, b_, c_) __builtin_amdgcn_mfma_f32_16x16x32_bf16((a_), (b_), (c_), 0, 0, 0)

// LDS-only barrier: order LDS, keep global loads/stores in flight (no vmcnt drain)
#define BAR_LDS() asm volatile("s_waitcnt lgkmcnt(0)\n\ts_barrier" ::: "memory")

// gate-row scale: i,f,o -> -log2e (sigmoid w/ negated arg), g -> 2*log2e (tanh)
DEV float gscale(int q) { return (q == 2) ? K2 : -L2E; }

DEV float fexp2(float x) { return __builtin_amdgcn_exp2f(x); }   // v_exp_f32
DEV float frcp(float x)  { return __builtin_amdgcn_rcpf(x); }
DEV float rcp1p(float e) { return frcp(1.f + e); }

DEV unsigned short f2bf(float x) {
    __hip_bfloat16 h = __float2bfloat16(x);
    unsigned short u;
    __builtin_memcpy(&u, &h, 2);
    return u;
}
DEV float asf(unsigned int u) {
    float f;
    __builtin_memcpy(&f, &u, 4);
    return f;
}
DEV unsigned int pk2(float lo, float hi) {   // packed bf16 pair (RNE)
    __hip_bfloat162 b2 = __float22bfloat162_rn(make_float2(lo, hi));
    unsigned int u;
    __builtin_memcpy(&u, &b2, 4);
    return u;
}
DEV f32x4 unp4(unsigned int a, unsigned int b) {   // 4 bf16 -> 4 f32
    f32x4 v;
    v[0] = asf(a << 16); v[1] = asf(a & 0xffff0000u);
    v[2] = asf(b << 16); v[3] = asf(b & 0xffff0000u);
    return v;
}
DEV bf16x8 pack8(const float* f) {
    bf16x8 v;
#pragma unroll
    for (int e = 0; e < 8; ++e) v[e] = (short)f2bf(f[e]);
    return v;
}

// Fused LSTM cell update from scaled gates (i,f,g,o in acc regs 0..3):
// updates cst, returns h. 5 exp + 3 rcp.
DEV float cellup(const f32x4& acc, float& cst) {
    float Ai = fexp2(acc[0]);            // e^-i
    float Bg = fexp2(acc[2]);            // e^2g
    float sf = rcp1p(fexp2(acc[1]));     // sigmoid(f)
    float ig = (Bg - 1.f) * frcp((1.f + Ai) * (1.f + Bg));  // sig(i)*tanh(g)
    cst = __builtin_fmaf(sf, cst, ig);
    float Cc = fexp2(K2 * cst);          // e^2c
    float Do = fexp2(acc[3]);            // e^-o
    return (Cc - 1.f) * frcp((1.f + Do) * (1.f + Cc));      // sig(o)*tanh(c)
}

// ============================ bi-LSTM (MFMA) ================================
// 1024 threads: dirs x 8 waves. Wave w' owns 8 cells [8w',8w'+8) per dir:
// gate pos g = 32w'+16mt+R <-> (q=R&3, hc=8w'+(R>>2)+4mt). Lane (lg,lc)
// holds cells {8w'+lg, 8w'+lg+4} (mt=0,1), batch col lc.
struct BiArgs {
    const float* x[7];
    const float* Wih[2];
    const float* Whh[2];
    const float* bih[2];
    const float* bhh[2];
    unsigned short* outs_bf;   // [3][B][T][HH] bf16 (traj only)
    float* hid;                // [7][B][HH] fp32
};

__global__ __launch_bounds__(1024) void k_bilstm_mfma(BiArgs a) {
    const int blk  = blockIdx.x;        // 56
    const int prob = blk >> 3;          // 0..6
    const int b0   = (blk & 7) * 16;
    const int tid  = threadIdx.x;
    const int dir  = tid >> 9;
    const int w    = (tid >> 6) & 7;    // wave-in-dir 0..7
    const int l    = tid & 63;
    const int lg   = l >> 4;
    const int lc   = l & 15;

    const float* Whh = a.Whh[dir];
    const float* Wih = a.Wih[dir];
    const float* bih = a.bih[dir];
    const float* bhh = a.bhh[dir];

    // A-frags: tile mt row R=lc -> orow = (lc&3)*H2 + 8w + (lc>>2) + 4mt
    const float sw = gscale(lc & 3);
    bf16x8 wf[2][2];
#pragma unroll
    for (int mt = 0; mt < 2; ++mt) {
#pragma unroll
        for (int kh = 0; kh < 2; ++kh) {
            int orow = (lc & 3) * H2 + 8 * w + (lc >> 2) + 4 * mt;
            float tmp[8];
#pragma unroll
            for (int e = 0; e < 8; ++e)
                tmp[e] = Whh[(size_t)orow * H2 + 32 * kh + 8 * lg + e] * sw;
            wf[mt][kh] = pack8(tmp);
        }
    }
    // acc-init: reg r, tile mt -> orow = r*H2 + 8w + lg + 4mt
    float bia[2][4], wx0[2][4], wx1[2][4];
#pragma unroll
    for (int mt = 0; mt < 2; ++mt)
#pragma unroll
        for (int r = 0; r < 4; ++r) {
            int orow = r * H2 + 8 * w + lg + 4 * mt;
            float s = gscale(r);
            bia[mt][r] = (bih[orow] + bhh[orow]) * s;
            wx0[mt][r] = Wih[orow * 2 + 0] * s;
            wx1[mt][r] = Wih[orow * 2 + 1] * s;
        }

    __shared__ unsigned short Hb[2][2][8][16][8];   // [dir][buf][cell>>3][batch][cell&7]
    if ((tid & 511) < 256)
        ((unsigned long long*)&Hb[tid >> 9][0][0][0][0])[tid & 255] = 0ULL;

    const bool isTraj = (prob >= 4);
    unsigned short* outp = a.outs_bf + (size_t)(isTraj ? (prob - 4) : 0) * BB * TT * HH;
    const float2* xg2 = (const float2*)a.x[prob];
    const int c = b0 + lc;

    float cst[2] = {0.f, 0.f};
    int cur = 0;
    float2 xrA = xg2[(size_t)c * TT + (dir ? TT - 1 : 0)];
    float2 xrB = xg2[(size_t)c * TT + (dir ? TT - 2 : 1)];
    __syncthreads();

#define BI_BODY(XR, T_)                                                          \
    {                                                                            \
        const int t = (T_);                                                      \
        f32x4 acc[2];                                                            \
        _Pragma("unroll")                                                        \
        for (int mt = 0; mt < 2; ++mt) {                                         \
            f32x4 v;                                                             \
            _Pragma("unroll")                                                    \
            for (int r = 0; r < 4; ++r)                                          \
                v[r] = __builtin_fmaf(wx0[mt][r], XR.x,                          \
                        __builtin_fmaf(wx1[mt][r], XR.y, bia[mt][r]));           \
            acc[mt] = v;                                                         \
        }                                                                        \
        {                                                                        \
            int tn = (t + 2 < TT) ? t + 2 : t;                                   \
            XR = xg2[(size_t)c * TT + (dir ? TT - 1 - tn : tn)];                 \
        }                                                                        \
        _Pragma("unroll")                                                        \
        for (int kh = 0; kh < 2; ++kh) {                                         \
            bf16x8 bfrag = *(const bf16x8*)&Hb[dir][cur][4 * kh + lg][lc][0];    \
            _Pragma("unroll")                                                    \
            for (int mt = 0; mt < 2; ++mt)                                       \
                acc[mt] = MFMA16(wf[mt][kh], bfrag, acc[mt]);                    \
        }                                                                        \
        const int nxt = cur ^ 1;                                                 \
        const int tcol = dir ? (TT - 1 - t) : t;                                 \
        float h0 = cellup(acc[0], cst[0]);                                       \
        float h1 = cellup(acc[1], cst[1]);                                       \
        unsigned short hb0 = f2bf(h0), hb1 = f2bf(h1);                           \
        Hb[dir][nxt][w][lc][lg]     = hb0;                                       \
        Hb[dir][nxt][w][lc][lg + 4] = hb1;                                       \
        if (isTraj) {                                                            \
            unsigned short* op = &outp[((size_t)c * TT + tcol) * HH              \
                                       + dir * H2 + 8 * w + lg];                 \
            op[0] = hb0;                                                         \
            op[4] = hb1;                                                         \
        }                                                                        \
        if (t == TT - 1) {                                                       \
            float* hd = &a.hid[((size_t)prob * BB + c) * HH + dir * H2           \
                               + 8 * w + lg];                                    \
            hd[0] = h0;                                                          \
            hd[4] = h1;                                                          \
        }                                                                        \
        BAR_LDS();                                                               \
        cur = nxt;                                                               \
    }

    for (int t2 = 0; t2 < TT; t2 += 2) {
        BI_BODY(xrA, t2)
        BI_BODY(xrB, t2 + 1)
    }
#undef BI_BODY
}

// ---------- WxB[p][k] = mve_Wih[j][k]*gscale(q) bf16, p=4h+q, k<128 ----------
__global__ void k_wxB(const float* __restrict__ Wm, unsigned short* __restrict__ WxB) {
    int idx = blockIdx.x * 256 + threadIdx.x;   // 512*128
    int p = idx >> 7, k = idx & 127;
    int j = (p & 3) * HH + (p >> 2);
    WxB[idx] = f2bf(Wm[(size_t)j * (2 * HH) + k] * gscale(p & 3));
}

// ------------- hp: (hidden_l @ WihR.T + bias) scaled, permuted rows ---------
__global__ __launch_bounds__(256) void k_hp(const float* __restrict__ hidl,
                                            const float* __restrict__ Wih,
                                            const float* __restrict__ bih,
                                            const float* __restrict__ bhh,
                                            float* __restrict__ hp) {
    int traj = blockIdx.x, b = blockIdx.y;
    int j = threadIdx.x;
    __shared__ float hs[HH];
    if (j < HH) hs[j] = hidl[((size_t)traj * BB + b) * HH + j];
    __syncthreads();
    const float4* hs4 = (const float4*)hs;
#pragma unroll
    for (int rr = 0; rr < 2; ++rr) {
        int row = j + 256 * rr;
        float acc = bih[row] + bhh[row];
        const float4* w4 = (const float4*)(Wih + (size_t)row * (2 * HH) + HH);
#pragma unroll
        for (int k4 = 0; k4 < HH / 4; ++k4) {
            float4 wv = w4[k4], hv = hs4[k4];
            acc += wv.x * hv.x + wv.y * hv.y + wv.z * hv.z + wv.w * hv.w;
        }
        int p = 4 * (row & 127) + (row >> 7);
        hp[((size_t)traj * BB + b) * GM + p] = acc * gscale(row >> 7);
    }
}

// ===== xproj MFMA GEMM: xpb[traj][m][p] = outs_bf[m][:] . WxB[p][:] + hp =====
__global__ __launch_bounds__(256) void k_xproj_mfma(
    const unsigned short* __restrict__ outs_bf,  // [3][65536][128]
    const unsigned short* __restrict__ WxB,      // [512][128]
    const float* __restrict__ hp,                // [3][128][512]
    unsigned short* __restrict__ xpb) {          // [3][65536][512]
    const int mb   = blockIdx.x;   // 0..511
    const int pb   = blockIdx.y;   // 0..3
    const int traj = blockIdx.z;
    const int tid  = threadIdx.x;
    const int w = tid >> 6, l = tid & 63, lg = l >> 4, lc = l & 15;
    const int m0 = mb * 128;
    const int p0 = pb * 128;
    const int c  = m0 >> 9;

    __shared__ unsigned short Xs[128 * 128];   // xp tile 32KB (XOR-swizzled)
    __shared__ unsigned short Ps[128 * 128];   // WxB tile 32KB / C-tile reuse

    const uint4* xg4 = (const uint4*)(outs_bf + ((size_t)traj * (BB * TT) + m0) * HH);
    const uint4* pg4 = (const uint4*)(WxB + (size_t)p0 * HH);
#pragma unroll
    for (int i = 0; i < 8; ++i) {
        int j = i * 256 + tid;               // 16B chunk 0..2047
        int byte = j * 16;
        int row = byte >> 8;
        int sb = byte ^ ((row & 7) << 4);
        *(uint4*)((char*)Xs + sb) = xg4[j];
        *(uint4*)((char*)Ps + sb) = pg4[j];
    }
    __syncthreads();

    bf16x8 xfrag[2][4];
#pragma unroll
    for (int xt = 0; xt < 2; ++xt)
#pragma unroll
        for (int kh = 0; kh < 4; ++kh) {
            int row = 32 * w + 16 * xt + lc;
            int byte = row * 256 + 64 * kh + 16 * lg;
            xfrag[xt][kh] = *(const bf16x8*)((const char*)Xs + (byte ^ ((row & 7) << 4)));
        }
    f32x4 acc[8][2];
#pragma unroll
    for (int pt = 0; pt < 8; ++pt)
#pragma unroll
        for (int xt = 0; xt < 2; ++xt)
#pragma unroll
            for (int r = 0; r < 4; ++r) acc[pt][xt][r] = 0.f;

#pragma unroll
    for (int pt = 0; pt < 8; ++pt) {
        bf16x8 pf[4];
#pragma unroll
        for (int kh = 0; kh < 4; ++kh) {
            int row = 16 * pt + lc;
            int byte = row * 256 + 64 * kh + 16 * lg;
            pf[kh] = *(const bf16x8*)((const char*)Ps + (byte ^ ((row & 7) << 4)));
        }
#pragma unroll
        for (int kh = 0; kh < 4; ++kh)
#pragma unroll
            for (int xt = 0; xt < 2; ++xt)
                acc[pt][xt] = MFMA16(pf[kh], xfrag[xt][kh], acc[pt][xt]);
    }
    __syncthreads();   // all Ps frag reads done before C-tile overwrite

#pragma unroll
    for (int pt = 0; pt < 8; ++pt) {
        float4 hv = *(const float4*)&hp[(((size_t)traj * BB + c)) * GM + p0 + 16 * pt + 4 * lg];
#pragma unroll
        for (int xt = 0; xt < 2; ++xt) {
            int mloc = 32 * w + 16 * xt + lc;
            int byte = mloc * 256 + (16 * pt + 4 * lg) * 2;
            uint2 u = make_uint2(pk2(acc[pt][xt][0] + hv.x, acc[pt][xt][1] + hv.y),
                                 pk2(acc[pt][xt][2] + hv.z, acc[pt][xt][3] + hv.w));
            *(uint2*)((char*)Ps + (byte ^ ((mloc & 7) << 4))) = u;
        }
    }
    __syncthreads();

    unsigned short* Cg = xpb + ((size_t)traj * (BB * TT) + m0) * GM + p0;
#pragma unroll
    for (int i = 0; i < 8; ++i) {
        int j = i * 256 + tid;               // chunk
        int r = j >> 4;                      // m-row local
        int cb = (j & 15) * 16;              // byte within 256B row
        uint4 v = *(const uint4*)((const char*)Ps + ((r * 256 + cb) ^ ((r & 7) << 4)));
        *(uint4*)((char*)(Cg + (size_t)r * GM) + cb) = v;
    }
}

// ============================= mve scan (MFMA) ==============================
// 1024 threads = 16 waves. Wave w owns cells [8w,8w+8): gate pos
// g = 32w+16mt+R <-> (q=R&3, hc=8w+(R>>2)+4mt). Lane (lg,lc) holds cells
// {8w+lg, 8w+lg+4}, batch col lc. xp col p = 4hc+q.
struct MveArgs {
    const unsigned short* xp;   // [3][B][T][512] bf16: scaled gates + hp folded
    const float* Whh;           // [512][128]
    float* mout;                // d_out+512: [3][B][T][HH] cell states
};

__global__ __launch_bounds__(1024) void k_mve_mfma(MveArgs a) {
    const int blk  = blockIdx.x;   // 24
    const int traj = blk >> 3;
    const int b0   = (blk & 7) * 16;
    const int tid  = threadIdx.x;
    const int w    = tid >> 6;     // 0..15
    const int l    = tid & 63;
    const int lg   = l >> 4;
    const int lc   = l & 15;
    const int c    = b0 + lc;

    // A-frags: tile mt row R=lc -> orow = (lc&3)*HH + 8w + (lc>>2) + 4mt
    const float sw = gscale(lc & 3);
    bf16x8 wf[2][4];
#pragma unroll
    for (int mt = 0; mt < 2; ++mt) {
#pragma unroll
        for (int kh = 0; kh < 4; ++kh) {
            int orow = (lc & 3) * HH + 8 * w + (lc >> 2) + 4 * mt;
            float tmp[8];
#pragma unroll
            for (int e = 0; e < 8; ++e)
                tmp[e] = a.Whh[(size_t)orow * HH + 32 * kh + 8 * lg + e] * sw;
            wf[mt][kh] = pack8(tmp);
        }
    }

    __shared__ unsigned short Hb[2][16][16][8];   // [buf][cell>>3][batch][cell&7]
    if (tid < 512) ((unsigned long long*)Hb)[tid] = 0ULL;   // zero buf 0 (4096B)

    // lane's gates: p = 32w + 4lg + 16mt + r
    const unsigned short* xrow = a.xp + (size_t)traj * BB * TT * GM
                               + (size_t)c * TT * GM + 32 * w + 4 * lg;
    float* mop = a.mout + (size_t)traj * BB * TT * HH
               + (size_t)c * TT * HH + 8 * w + lg;

    float cst[2] = {0.f, 0.f};
    int cur = 0;
    // 2-deep xp pipeline
    uint2 xqA0 = *(const uint2*)xrow;
    uint2 xqA1 = *(const uint2*)(xrow + 16);
    uint2 xqB0 = *(const uint2*)(xrow + GM);
    uint2 xqB1 = *(const uint2*)(xrow + GM + 16);
    __syncthreads();

#define MVE_BODY(XQ0, XQ1, T_)                                                   \
    {                                                                            \
        const int t = (T_);                                                      \
        f32x4 acc[2];                                                            \
        acc[0] = unp4(XQ0.x, XQ0.y);                                             \
        acc[1] = unp4(XQ1.x, XQ1.y);                                             \
        {   /* re-issue this buffer's loads for t+2 */                           \
            const unsigned short* pf = xrow                                      \
                + (size_t)((t + 2 < TT) ? t + 2 : t) * GM;                       \
            XQ0 = *(const uint2*)pf;                                             \
            XQ1 = *(const uint2*)(pf + 16);                                      \
        }                                                                        \
        _Pragma("unroll")                                                        \
        for (int kh = 0; kh < 4; ++kh) {                                         \
            bf16x8 bfrag = *(const bf16x8*)&Hb[cur][4 * kh + lg][lc][0];         \
            _Pragma("unroll")                                                    \
            for (int mt = 0; mt < 2; ++mt)                                       \
                acc[mt] = MFMA16(wf[mt][kh], bfrag, acc[mt]);                    \
        }                                                                        \
        const int nxt = cur ^ 1;                                                 \
        float h0 = cellup(acc[0], cst[0]);                                       \
        float h1 = cellup(acc[1], cst[1]);                                       \
        Hb[nxt][w][lc][lg]     = f2bf(h0);                                       \
        Hb[nxt][w][lc][lg + 4] = f2bf(h1);                                       \
        {   /* CELL state: non-temporal, 4 consecutive lanes -> 16B runs */      \
            float* mo = mop + (size_t)t * HH;                                    \
            __builtin_nontemporal_store(cst[0], mo);                             \
            __builtin_nontemporal_store(cst[1], mo + 4);                         \
        }                                                                        \
        BAR_LDS();                                                               \
        cur = nxt;                                                               \
    }

    for (int t2 = 0; t2 < TT; t2 += 2) {
        MVE_BODY(xqA0, xqA1, t2)
        MVE_BODY(xqB0, xqB1, t2 + 1)
    }
#undef MVE_BODY
}

// ----------------------------------------------------------------- sim ------
__global__ __launch_bounds__(128) void k_sim(const float* __restrict__ hid,
                                             const float* __restrict__ Wi, const float* __restrict__ bi,
                                             const float* __restrict__ Wc, const float* __restrict__ bc,
                                             const float* __restrict__ Wo, const float* __restrict__ bo,
                                             float* __restrict__ simv) {
    int which = blockIdx.x >> 7;
    int b = blockIdx.x & 127;
    int j = threadIdx.x;
    __shared__ float hs[HH];
    hs[j] = hid[((size_t)which * BB + b) * HH + j];
    __syncthreads();
    float ai = bi[j], ac = bc[j], ao = bo[j];
    const float4* wi4 = (const float4*)(Wi + (size_t)j * HH);
    const float4* wc4 = (const float4*)(Wc + (size_t)j * HH);
    const float4* wo4 = (const float4*)(Wo + (size_t)j * HH);
#pragma unroll
    for (int k4 = 0; k4 < HH / 4; ++k4) {
        float4 h = ((const float4*)hs)[k4];
        float4 vi = wi4[k4]; ai += vi.x*h.x + vi.y*h.y + vi.z*h.z + vi.w*h.w;
        float4 vc = wc4[k4]; ac += vc.x*h.x + vc.y*h.y + vc.z*h.z + vc.w*h.w;
        float4 vo = wo4[k4]; ao += vo.x*h.x + vo.y*h.y + vo.z*h.z + vo.w*h.w;
    }
    float Cv = (1.f / (1.f + __expf(-ai))) * tanhf(ac);
    float v = (1.f / (1.f + __expf(-ao))) * tanhf(Cv) + hs[j];
    simv[((size_t)which * BB + b) * HH + j] = v;
}

// ------------------------------------------------------------------ l2 ------
__global__ __launch_bounds__(64) void k_l2(const float* __restrict__ simv,
                                           float* __restrict__ out) {
    int p = blockIdx.x >> 7;
    int b = blockIdx.x & 127;
    int aw, cw;
    switch (p) {
        case 0: aw = 0; cw = 2; break;
        case 1: aw = 1; cw = 3; break;
        case 2: aw = 4; cw = 5; break;
        default: aw = 4; cw = 6; break;
    }
    int l = threadIdx.x;
    const float* va = simv + ((size_t)aw * BB + b) * HH;
    const float* vc = simv + ((size_t)cw * BB + b) * HH;
    float d0 = va[l] - vc[l];
    float d1 = va[l + 64] - vc[l + 64];
    float s = d0 * d0 + d1 * d1;
#pragma unroll
    for (int m = 32; m >= 1; m >>= 1) s += __shfl_xor(s, m, 64);
    if (l == 0) out[p * BB + b] = expf(-sqrtf(s));
}

// -------------------------------------------------------------- launcher ----
extern "C" void kernel_launch(void* const* d_in, const int* in_sizes, int n_in,
                              void* d_out_v, int out_size, void* d_ws, size_t ws_size,
                              hipStream_t stream) {
    const float* mWih  = (const float*)d_in[15];
    const float* mWhh  = (const float*)d_in[16];
    const float* mbih  = (const float*)d_in[17];
    const float* mbhh  = (const float*)d_in[18];
    const float* sWi   = (const float*)d_in[19];
    const float* sbi   = (const float*)d_in[20];
    const float* sWc   = (const float*)d_in[21];
    const float* sbc   = (const float*)d_in[22];
    const float* sWo   = (const float*)d_in[23];
    const float* sbo   = (const float*)d_in[24];

    constexpr size_t OUTSBF_LEN = (size_t)3 * BB * TT * HH;   // bf16
    constexpr size_t HID_LEN    = (size_t)7 * BB * HH;        // f32
    constexpr size_t WXB_LEN    = (size_t)GM * HH;            // bf16
    constexpr size_t SIMV_LEN   = HID_LEN;                    // f32
    constexpr size_t HP_LEN     = (size_t)3 * BB * GM;        // f32
    constexpr size_t XP_LEN     = (size_t)3 * BB * TT * GM;   // bf16

    char* ws = (char*)d_ws;
    unsigned short* outs_bf = (unsigned short*)ws;                 ws += OUTSBF_LEN * 2;
    float*          hid     = (float*)ws;                          ws += HID_LEN * 4;
    unsigned short* WxB     = (unsigned short*)ws;                 ws += WXB_LEN * 2;
    float*          simv    = (float*)ws;                          ws += SIMV_LEN * 4;
    float*          hp      = (float*)ws;                          ws += HP_LEN * 4;
    unsigned short* xpb     = (unsigned short*)ws;                 ws += XP_LEN * 2;

    float* dout = (float*)d_out_v;
    float* mout = dout + 512;

    BiArgs ba;
    for (int i = 0; i < 7; ++i) ba.x[i] = (const float*)d_in[i];
    ba.Wih[0] = (const float*)d_in[7];  ba.Whh[0] = (const float*)d_in[8];
    ba.bih[0] = (const float*)d_in[9];  ba.bhh[0] = (const float*)d_in[10];
    ba.Wih[1] = (const float*)d_in[11]; ba.Whh[1] = (const float*)d_in[12];
    ba.bih[1] = (const float*)d_in[13]; ba.bhh[1] = (const float*)d_in[14];
    ba.outs_bf = outs_bf; ba.hid = hid;

    k_wxB<<<256, 256, 0, stream>>>(mWih, WxB);
    k_bilstm_mfma<<<56, 1024, 0, stream>>>(ba);
    k_hp<<<dim3(3, BB), 256, 0, stream>>>(hid + (size_t)4 * BB * HH, mWih, mbih, mbhh, hp);

    dim3 gx(BB * TT / 128, GM / 128, 3);
    k_xproj_mfma<<<gx, 256, 0, stream>>>(outs_bf, WxB, hp, xpb);

    MveArgs ma;
    ma.xp = xpb; ma.Whh = mWhh; ma.mout = mout;
    k_mve_mfma<<<24, 1024, 0, stream>>>(ma);

    k_sim<<<7 * BB, 128, 0, stream>>>(hid, sWi, sbi, sWc, sbc, sWo, sbo, simv);
    k_l2<<<4 * BB, 64, 0, stream>>>(simv, dout);
}

// Round 12
// 963.473 us; speedup vs baseline: 1.5330x; 1.5330x over previous
//
#include <hip/hip_runtime.h>
#include <hip/hip_bf16.h>

#define DEV __device__ __forceinline__

constexpr int BB  = 128;   // batch
constexpr int TT  = 512;   // seq len
constexpr int HH  = 128;   // concat hidden
constexpr int H2  = 64;    // per-direction hidden
constexpr int GM  = 512;   // 4*HH (mve gates)

constexpr float L2E = 1.4426950408889634f;
constexpr float K2  = 2.0f * L2E;

typedef __attribute__((ext_vector_type(8))) short bf16x8;
typedef __attribute__((ext_vector_type(4))) float f32x4;

#define MFMA16(a_, b_, c_) __builtin_amdgcn_mfma_f32_16x16x32_bf16((a_), (b_), (c_), 0, 0, 0)

// LDS-only barrier: order LDS, keep global loads/stores in flight (no vmcnt drain)
#define BAR_LDS() asm volatile("s_waitcnt lgkmcnt(0)\n\ts_barrier" ::: "memory")

// gate-row scale: i,f,o -> -log2e (sigmoid w/ negated arg), g -> 2*log2e (tanh)
DEV float gscale(int q) { return (q == 2) ? K2 : -L2E; }

DEV float fexp2(float x) { return __builtin_amdgcn_exp2f(x); }   // v_exp_f32
DEV float frcp(float x)  { return __builtin_amdgcn_rcpf(x); }
DEV float rcp1p(float e) { return frcp(1.f + e); }

DEV unsigned short f2bf(float x) {
    __hip_bfloat16 h = __float2bfloat16(x);
    unsigned short u;
    __builtin_memcpy(&u, &h, 2);
    return u;
}
DEV float asf(unsigned int u) {
    float f;
    __builtin_memcpy(&f, &u, 4);
    return f;
}
DEV unsigned int pk2(float lo, float hi) {   // packed bf16 pair (RNE)
    __hip_bfloat162 b2 = __float22bfloat162_rn(make_float2(lo, hi));
    unsigned int u;
    __builtin_memcpy(&u, &b2, 4);
    return u;
}
DEV f32x4 unp4(unsigned int a, unsigned int b) {   // 4 bf16 -> 4 f32
    f32x4 v;
    v[0] = asf(a << 16); v[1] = asf(a & 0xffff0000u);
    v[2] = asf(b << 16); v[3] = asf(b & 0xffff0000u);
    return v;
}
DEV bf16x8 pack8(const float* f) {
    bf16x8 v;
#pragma unroll
    for (int e = 0; e < 8; ++e) v[e] = (short)f2bf(f[e]);
    return v;
}

// Fused LSTM cell update from scaled gates (i,f,g,o in acc regs 0..3):
// updates cst, returns h. 5 exp + 3 rcp.
DEV float cellup(const f32x4& acc, float& cst) {
    float Ai = fexp2(acc[0]);            // e^-i
    float Bg = fexp2(acc[2]);            // e^2g
    float sf = rcp1p(fexp2(acc[1]));     // sigmoid(f)
    float ig = (Bg - 1.f) * frcp((1.f + Ai) * (1.f + Bg));  // sig(i)*tanh(g)
    cst = __builtin_fmaf(sf, cst, ig);
    float Cc = fexp2(K2 * cst);          // e^2c
    float Do = fexp2(acc[3]);            // e^-o
    return (Cc - 1.f) * frcp((1.f + Do) * (1.f + Cc));      // sig(o)*tanh(c)
}

// ============================ bi-LSTM (MFMA) ================================
// Round-10 shape (known good): 512 threads, waves 0-3 fwd / 4-7 bwd.
// Acc reg r: q=r, cell hc = 16w+4lg+mt -> lane holds 4 consecutive cells.
struct BiArgs {
    const float* x[7];
    const float* Wih[2];
    const float* Whh[2];
    const float* bih[2];
    const float* bhh[2];
    unsigned short* outs_bf;   // [3][B][T][HH] bf16 (traj only)
    float* hid;                // [7][B][HH] fp32
};

__global__ __launch_bounds__(512) void k_bilstm_mfma(BiArgs a) {
    const int blk  = blockIdx.x;        // 56
    const int prob = blk >> 3;          // 0..6
    const int b0   = (blk & 7) * 16;
    const int tid  = threadIdx.x;
    const int dir  = tid >> 8;
    const int w    = (tid >> 6) & 3;    // wave-in-dir 0..3
    const int l    = tid & 63;
    const int lg   = l >> 4;
    const int lc   = l & 15;

    const float* Whh = a.Whh[dir];
    const float* Wih = a.Wih[dir];
    const float* bih = a.bih[dir];
    const float* bhh = a.bhh[dir];

    const float sw = gscale(lc & 3);
    bf16x8 wf[4][2];
#pragma unroll
    for (int mt = 0; mt < 4; ++mt) {
#pragma unroll
        for (int kh = 0; kh < 2; ++kh) {
            int orow = (lc & 3) * H2 + 16 * w + 4 * (lc >> 2) + mt;
            float tmp[8];
#pragma unroll
            for (int e = 0; e < 8; ++e)
                tmp[e] = Whh[(size_t)orow * H2 + 32 * kh + 8 * lg + e] * sw;
            wf[mt][kh] = pack8(tmp);
        }
    }
    float bia[4][4], wx0[4][4], wx1[4][4];
#pragma unroll
    for (int mt = 0; mt < 4; ++mt)
#pragma unroll
        for (int r = 0; r < 4; ++r) {
            int orow = r * H2 + 16 * w + 4 * lg + mt;
            float s = gscale(r);
            bia[mt][r] = (bih[orow] + bhh[orow]) * s;
            wx0[mt][r] = Wih[orow * 2 + 0] * s;
            wx1[mt][r] = Wih[orow * 2 + 1] * s;
        }

    __shared__ unsigned short Hb[2][2][8][16][8];   // [dir][buf][k>>3][batch][k&7]
    ((unsigned long long*)&Hb[tid >> 8][0][0][0][0])[tid & 255] = 0ULL;

    const bool isTraj = (prob >= 4);
    unsigned short* outp = a.outs_bf + (size_t)(isTraj ? (prob - 4) : 0) * BB * TT * HH;
    const float2* xg2 = (const float2*)a.x[prob];
    const int c = b0 + lc;

    float cst[4] = {0.f, 0.f, 0.f, 0.f};
    int cur = 0;
    float2 xrA = xg2[(size_t)c * TT + (dir ? TT - 1 : 0)];
    float2 xrB = xg2[(size_t)c * TT + (dir ? TT - 2 : 1)];
    __syncthreads();

#define BI_BODY(XR, T_)                                                          \
    {                                                                            \
        const int t = (T_);                                                      \
        f32x4 acc[4];                                                            \
        _Pragma("unroll")                                                        \
        for (int mt = 0; mt < 4; ++mt) {                                         \
            f32x4 v;                                                             \
            _Pragma("unroll")                                                    \
            for (int r = 0; r < 4; ++r)                                          \
                v[r] = __builtin_fmaf(wx0[mt][r], XR.x,                          \
                        __builtin_fmaf(wx1[mt][r], XR.y, bia[mt][r]));           \
            acc[mt] = v;                                                         \
        }                                                                        \
        {                                                                        \
            int tn = (t + 2 < TT) ? t + 2 : t;                                   \
            XR = xg2[(size_t)c * TT + (dir ? TT - 1 - tn : tn)];                 \
        }                                                                        \
        _Pragma("unroll")                                                        \
        for (int kh = 0; kh < 2; ++kh) {                                         \
            bf16x8 bfrag = *(const bf16x8*)&Hb[dir][cur][4 * kh + lg][lc][0];    \
            _Pragma("unroll")                                                    \
            for (int mt = 0; mt < 4; ++mt)                                       \
                acc[mt] = MFMA16(wf[mt][kh], bfrag, acc[mt]);                    \
        }                                                                        \
        const int nxt = cur ^ 1;                                                 \
        const int tcol = dir ? (TT - 1 - t) : t;                                 \
        float4 h4;                                                               \
        float* hp4 = &h4.x;                                                      \
        _Pragma("unroll")                                                        \
        for (int mt = 0; mt < 4; ++mt)                                           \
            hp4[mt] = cellup(acc[mt], cst[mt]);                                  \
        uint2 hpk = make_uint2(pk2(h4.x, h4.y), pk2(h4.z, h4.w));                \
        {                                                                        \
            int pp = 16 * w + 4 * lg;                                            \
            *(uint2*)&Hb[dir][nxt][pp >> 3][lc][pp & 7] = hpk;                   \
        }                                                                        \
        if (isTraj)                                                              \
            *(uint2*)&outp[((size_t)c * TT + tcol) * HH + dir * H2               \
                           + 16 * w + 4 * lg] = hpk;                             \
        if (t == TT - 1)                                                         \
            *(float4*)&a.hid[((size_t)prob * BB + c) * HH + dir * H2             \
                             + 16 * w + 4 * lg] = h4;                            \
        BAR_LDS();                                                               \
        cur = nxt;                                                               \
    }

    for (int t2 = 0; t2 < TT; t2 += 2) {
        BI_BODY(xrA, t2)
        BI_BODY(xrB, t2 + 1)
    }
#undef BI_BODY
}

// ---------- WxB[p][k] = mve_Wih[j][k]*gscale(q) bf16, p=4h+q, k<128 ----------
__global__ void k_wxB(const float* __restrict__ Wm, unsigned short* __restrict__ WxB) {
    int idx = blockIdx.x * 256 + threadIdx.x;   // 512*128
    int p = idx >> 7, k = idx & 127;
    int j = (p & 3) * HH + (p >> 2);
    WxB[idx] = f2bf(Wm[(size_t)j * (2 * HH) + k] * gscale(p & 3));
}

// ------------- hp: (hidden_l @ WihR.T + bias) scaled, permuted rows ---------
__global__ __launch_bounds__(256) void k_hp(const float* __restrict__ hidl,
                                            const float* __restrict__ Wih,
                                            const float* __restrict__ bih,
                                            const float* __restrict__ bhh,
                                            float* __restrict__ hp) {
    int traj = blockIdx.x, b = blockIdx.y;
    int j = threadIdx.x;
    __shared__ float hs[HH];
    if (j < HH) hs[j] = hidl[((size_t)traj * BB + b) * HH + j];
    __syncthreads();
    const float4* hs4 = (const float4*)hs;
#pragma unroll
    for (int rr = 0; rr < 2; ++rr) {
        int row = j + 256 * rr;
        float acc = bih[row] + bhh[row];
        const float4* w4 = (const float4*)(Wih + (size_t)row * (2 * HH) + HH);
#pragma unroll
        for (int k4 = 0; k4 < HH / 4; ++k4) {
            float4 wv = w4[k4], hv = hs4[k4];
            acc += wv.x * hv.x + wv.y * hv.y + wv.z * hv.z + wv.w * hv.w;
        }
        int p = 4 * (row & 127) + (row >> 7);
        hp[((size_t)traj * BB + b) * GM + p] = acc * gscale(row >> 7);
    }
}

// ===== xproj MFMA GEMM: xpb[traj][m][p] = outs_bf[m][:] . WxB[p][:] + hp =====
__global__ __launch_bounds__(256) void k_xproj_mfma(
    const unsigned short* __restrict__ outs_bf,  // [3][65536][128]
    const unsigned short* __restrict__ WxB,      // [512][128]
    const float* __restrict__ hp,                // [3][128][512]
    unsigned short* __restrict__ xpb) {          // [3][65536][512]
    const int mb   = blockIdx.x;   // 0..511
    const int pb   = blockIdx.y;   // 0..3
    const int traj = blockIdx.z;
    const int tid  = threadIdx.x;
    const int w = tid >> 6, l = tid & 63, lg = l >> 4, lc = l & 15;
    const int m0 = mb * 128;
    const int p0 = pb * 128;
    const int c  = m0 >> 9;

    __shared__ unsigned short Xs[128 * 128];   // xp tile 32KB (XOR-swizzled)
    __shared__ unsigned short Ps[128 * 128];   // WxB tile 32KB / C-tile reuse

    const uint4* xg4 = (const uint4*)(outs_bf + ((size_t)traj * (BB * TT) + m0) * HH);
    const uint4* pg4 = (const uint4*)(WxB + (size_t)p0 * HH);
#pragma unroll
    for (int i = 0; i < 8; ++i) {
        int j = i * 256 + tid;               // 16B chunk 0..2047
        int byte = j * 16;
        int row = byte >> 8;
        int sb = byte ^ ((row & 7) << 4);
        *(uint4*)((char*)Xs + sb) = xg4[j];
        *(uint4*)((char*)Ps + sb) = pg4[j];
    }
    __syncthreads();

    bf16x8 xfrag[2][4];
#pragma unroll
    for (int xt = 0; xt < 2; ++xt)
#pragma unroll
        for (int kh = 0; kh < 4; ++kh) {
            int row = 32 * w + 16 * xt + lc;
            int byte = row * 256 + 64 * kh + 16 * lg;
            xfrag[xt][kh] = *(const bf16x8*)((const char*)Xs + (byte ^ ((row & 7) << 4)));
        }
    f32x4 acc[8][2];
#pragma unroll
    for (int pt = 0; pt < 8; ++pt)
#pragma unroll
        for (int xt = 0; xt < 2; ++xt)
#pragma unroll
            for (int r = 0; r < 4; ++r) acc[pt][xt][r] = 0.f;

#pragma unroll
    for (int pt = 0; pt < 8; ++pt) {
        bf16x8 pf[4];
#pragma unroll
        for (int kh = 0; kh < 4; ++kh) {
            int row = 16 * pt + lc;
            int byte = row * 256 + 64 * kh + 16 * lg;
            pf[kh] = *(const bf16x8*)((const char*)Ps + (byte ^ ((row & 7) << 4)));
        }
#pragma unroll
        for (int kh = 0; kh < 4; ++kh)
#pragma unroll
            for (int xt = 0; xt < 2; ++xt)
                acc[pt][xt] = MFMA16(pf[kh], xfrag[xt][kh], acc[pt][xt]);
    }
    __syncthreads();   // all Ps frag reads done before C-tile overwrite

#pragma unroll
    for (int pt = 0; pt < 8; ++pt) {
        float4 hv = *(const float4*)&hp[(((size_t)traj * BB + c)) * GM + p0 + 16 * pt + 4 * lg];
#pragma unroll
        for (int xt = 0; xt < 2; ++xt) {
            int mloc = 32 * w + 16 * xt + lc;
            int byte = mloc * 256 + (16 * pt + 4 * lg) * 2;
            uint2 u = make_uint2(pk2(acc[pt][xt][0] + hv.x, acc[pt][xt][1] + hv.y),
                                 pk2(acc[pt][xt][2] + hv.z, acc[pt][xt][3] + hv.w));
            *(uint2*)((char*)Ps + (byte ^ ((mloc & 7) << 4))) = u;
        }
    }
    __syncthreads();

    unsigned short* Cg = xpb + ((size_t)traj * (BB * TT) + m0) * GM + p0;
#pragma unroll
    for (int i = 0; i < 8; ++i) {
        int j = i * 256 + tid;               // chunk
        int r = j >> 4;                      // m-row local
        int cb = (j & 15) * 16;              // byte within 256B row
        uint4 v = *(const uint4*)((const char*)Ps + ((r * 256 + cb) ^ ((r & 7) << 4)));
        *(uint4*)((char*)(Cg + (size_t)r * GM) + cb) = v;
    }
}

// ============================= mve scan (MFMA) ==============================
// 1024 threads = 16 waves (4/SIMD). Wave w owns cells [8w,8w+8):
// gate tile g = 32w+16mt+R <-> (q=R&3, hc=8w+2*(R>>2)+mt). Lane (lg,lc)
// holds cells {8w+2lg, 8w+2lg+1} (CONSECUTIVE pair -> vector stores).
struct MveArgs {
    const unsigned short* xp;   // [3][B][T][512] bf16: scaled gates + hp folded
    const float* Whh;           // [512][128]
    float* mout;                // d_out+512: [3][B][T][HH] cell states
};

__global__ __launch_bounds__(1024) void k_mve_mfma(MveArgs a) {
    const int blk  = blockIdx.x;   // 24
    const int traj = blk >> 3;
    const int b0   = (blk & 7) * 16;
    const int tid  = threadIdx.x;
    const int w    = tid >> 6;     // 0..15
    const int l    = tid & 63;
    const int lg   = l >> 4;
    const int lc   = l & 15;
    const int c    = b0 + lc;

    // A-frags: tile mt row R=lc -> orow = (lc&3)*HH + 8w + 2*(lc>>2) + mt
    const float sw = gscale(lc & 3);
    bf16x8 wf[2][4];
#pragma unroll
    for (int mt = 0; mt < 2; ++mt) {
#pragma unroll
        for (int kh = 0; kh < 4; ++kh) {
            int orow = (lc & 3) * HH + 8 * w + 2 * (lc >> 2) + mt;
            float tmp[8];
#pragma unroll
            for (int e = 0; e < 8; ++e)
                tmp[e] = a.Whh[(size_t)orow * HH + 32 * kh + 8 * lg + e] * sw;
            wf[mt][kh] = pack8(tmp);
        }
    }

    __shared__ unsigned short Hb[2][16][16][8];   // [buf][cell>>3][batch][cell&7]
    if (tid < 512) ((unsigned long long*)Hb)[tid] = 0ULL;   // zero buf 0 (4096B)

    // lane's gates: cells 8w+2lg+{0,1} -> xp cols [32w+8lg, 32w+8lg+8) = uint4
    const unsigned short* xrow = a.xp + (size_t)traj * BB * TT * GM
                               + (size_t)c * TT * GM + 32 * w + 8 * lg;
    float* mop = a.mout + (size_t)traj * BB * TT * HH
               + (size_t)c * TT * HH + 8 * w + 2 * lg;

    float cst[2] = {0.f, 0.f};
    int cur = 0;
    // 2-deep xp pipeline
    uint4 xqA = *(const uint4*)xrow;
    uint4 xqB = *(const uint4*)(xrow + GM);
    __syncthreads();

#define MVE_BODY(XQ, T_)                                                         \
    {                                                                            \
        const int t = (T_);                                                      \
        f32x4 acc[2];                                                            \
        acc[0] = unp4(XQ.x, XQ.y);                                               \
        acc[1] = unp4(XQ.z, XQ.w);                                               \
        {   /* re-issue this buffer's load for t+2 */                            \
            const unsigned short* pf = xrow                                      \
                + (size_t)((t + 2 < TT) ? t + 2 : t) * GM;                       \
            XQ = *(const uint4*)pf;                                              \
        }                                                                        \
        _Pragma("unroll")                                                        \
        for (int kh = 0; kh < 4; ++kh) {                                         \
            bf16x8 bfrag = *(const bf16x8*)&Hb[cur][4 * kh + lg][lc][0];         \
            _Pragma("unroll")                                                    \
            for (int mt = 0; mt < 2; ++mt)                                       \
                acc[mt] = MFMA16(wf[mt][kh], bfrag, acc[mt]);                    \
        }                                                                        \
        const int nxt = cur ^ 1;                                                 \
        float h0 = cellup(acc[0], cst[0]);                                       \
        float h1 = cellup(acc[1], cst[1]);                                       \
        *(unsigned int*)&Hb[nxt][w][lc][2 * lg] = pk2(h0, h1);                   \
        {   /* CELL state: one float2 (consecutive cells) */                     \
            *(float2*)(mop + (size_t)t * HH) = make_float2(cst[0], cst[1]);      \
        }                                                                        \
        BAR_LDS();                                                               \
        cur = nxt;                                                               \
    }

    for (int t2 = 0; t2 < TT; t2 += 2) {
        MVE_BODY(xqA, t2)
        MVE_BODY(xqB, t2 + 1)
    }
#undef MVE_BODY
}

// ----------------------------------------------------------------- sim ------
__global__ __launch_bounds__(128) void k_sim(const float* __restrict__ hid,
                                             const float* __restrict__ Wi, const float* __restrict__ bi,
                                             const float* __restrict__ Wc, const float* __restrict__ bc,
                                             const float* __restrict__ Wo, const float* __restrict__ bo,
                                             float* __restrict__ simv) {
    int which = blockIdx.x >> 7;
    int b = blockIdx.x & 127;
    int j = threadIdx.x;
    __shared__ float hs[HH];
    hs[j] = hid[((size_t)which * BB + b) * HH + j];
    __syncthreads();
    float ai = bi[j], ac = bc[j], ao = bo[j];
    const float4* wi4 = (const float4*)(Wi + (size_t)j * HH);
    const float4* wc4 = (const float4*)(Wc + (size_t)j * HH);
    const float4* wo4 = (const float4*)(Wo + (size_t)j * HH);
#pragma unroll
    for (int k4 = 0; k4 < HH / 4; ++k4) {
        float4 h = ((const float4*)hs)[k4];
        float4 vi = wi4[k4]; ai += vi.x*h.x + vi.y*h.y + vi.z*h.z + vi.w*h.w;
        float4 vc = wc4[k4]; ac += vc.x*h.x + vc.y*h.y + vc.z*h.z + vc.w*h.w;
        float4 vo = wo4[k4]; ao += vo.x*h.x + vo.y*h.y + vo.z*h.z + vo.w*h.w;
    }
    float Cv = (1.f / (1.f + __expf(-ai))) * tanhf(ac);
    float v = (1.f / (1.f + __expf(-ao))) * tanhf(Cv) + hs[j];
    simv[((size_t)which * BB + b) * HH + j] = v;
}

// ------------------------------------------------------------------ l2 ------
__global__ __launch_bounds__(64) void k_l2(const float* __restrict__ simv,
                                           float* __restrict__ out) {
    int p = blockIdx.x >> 7;
    int b = blockIdx.x & 127;
    int aw, cw;
    switch (p) {
        case 0: aw = 0; cw = 2; break;
        case 1: aw = 1; cw = 3; break;
        case 2: aw = 4; cw = 5; break;
        default: aw = 4; cw = 6; break;
    }
    int l = threadIdx.x;
    const float* va = simv + ((size_t)aw * BB + b) * HH;
    const float* vc = simv + ((size_t)cw * BB + b) * HH;
    float d0 = va[l] - vc[l];
    float d1 = va[l + 64] - vc[l + 64];
    float s = d0 * d0 + d1 * d1;
#pragma unroll
    for (int m = 32; m >= 1; m >>= 1) s += __shfl_xor(s, m, 64);
    if (l == 0) out[p * BB + b] = expf(-sqrtf(s));
}

// -------------------------------------------------------------- launcher ----
extern "C" void kernel_launch(void* const* d_in, const int* in_sizes, int n_in,
                              void* d_out_v, int out_size, void* d_ws, size_t ws_size,
                              hipStream_t stream) {
    const float* mWih  = (const float*)d_in[15];
    const float* mWhh  = (const float*)d_in[16];
    const float* mbih  = (const float*)d_in[17];
    const float* mbhh  = (const float*)d_in[18];
    const float* sWi   = (const float*)d_in[19];
    const float* sbi   = (const float*)d_in[20];
    const float* sWc   = (const float*)d_in[21];
    const float* sbc   = (const float*)d_in[22];
    const float* sWo   = (const float*)d_in[23];
    const float* sbo   = (const float*)d_in[24];

    constexpr size_t OUTSBF_LEN = (size_t)3 * BB * TT * HH;   // bf16
    constexpr size_t HID_LEN    = (size_t)7 * BB * HH;        // f32
    constexpr size_t WXB_LEN    = (size_t)GM * HH;            // bf16
    constexpr size_t SIMV_LEN   = HID_LEN;                    // f32
    constexpr size_t HP_LEN     = (size_t)3 * BB * GM;        // f32
    constexpr size_t XP_LEN     = (size_t)3 * BB * TT * GM;   // bf16

    char* ws = (char*)d_ws;
    unsigned short* outs_bf = (unsigned short*)ws;                 ws += OUTSBF_LEN * 2;
    float*          hid     = (float*)ws;                          ws += HID_LEN * 4;
    unsigned short* WxB     = (unsigned short*)ws;                 ws += WXB_LEN * 2;
    float*          simv    = (float*)ws;                          ws += SIMV_LEN * 4;
    float*          hp      = (float*)ws;                          ws += HP_LEN * 4;
    unsigned short* xpb     = (unsigned short*)ws;                 ws += XP_LEN * 2;

    float* dout = (float*)d_out_v;
    float* mout = dout + 512;

    BiArgs ba;
    for (int i = 0; i < 7; ++i) ba.x[i] = (const float*)d_in[i];
    ba.Wih[0] = (const float*)d_in[7];  ba.Whh[0] = (const float*)d_in[8];
    ba.bih[0] = (const float*)d_in[9];  ba.bhh[0] = (const float*)d_in[10];
    ba.Wih[1] = (const float*)d_in[11]; ba.Whh[1] = (const float*)d_in[12];
    ba.bih[1] = (const float*)d_in[13]; ba.bhh[1] = (const float*)d_in[14];
    ba.outs_bf = outs_bf; ba.hid = hid;

    k_wxB<<<256, 256, 0, stream>>>(mWih, WxB);
    k_bilstm_mfma<<<56, 512, 0, stream>>>(ba);
    k_hp<<<dim3(3, BB), 256, 0, stream>>>(hid + (size_t)4 * BB * HH, mWih, mbih, mbhh, hp);

    dim3 gx(BB * TT / 128, GM / 128, 3);
    k_xproj_mfma<<<gx, 256, 0, stream>>>(outs_bf, WxB, hp, xpb);

    MveArgs ma;
    ma.xp = xpb; ma.Whh = mWhh; ma.mout = mout;
    k_mve_mfma<<<24, 1024, 0, stream>>>(ma);

    k_sim<<<7 * BB, 128, 0, stream>>>(hid, sWi, sbi, sWc, sbc, sWo, sbo, simv);
    k_l2<<<4 * BB, 64, 0, stream>>>(simv, dout);
}

// Round 13
// 905.251 us; speedup vs baseline: 1.6315x; 1.0643x over previous
//
#include <hip/hip_runtime.h>
#include <hip/hip_bf16.h>

#define DEV __device__ __forceinline__

constexpr int BB  = 128;   // batch
constexpr int TT  = 512;   // seq len
constexpr int HH  = 128;   // concat hidden
constexpr int H2  = 64;    // per-direction hidden
constexpr int GM  = 512;   // 4*HH (mve gates)

constexpr float L2E = 1.4426950408889634f;
constexpr float K2  = 2.0f * L2E;

typedef __attribute__((ext_vector_type(8))) short bf16x8;
typedef __attribute__((ext_vector_type(4))) float f32x4;

#define MFMA16(a_, b_, c_) __builtin_amdgcn_mfma_f32_16x16x32_bf16((a_), (b_), (c_), 0, 0, 0)

// LDS-only barrier: order LDS, keep global loads/stores in flight (no vmcnt drain)
#define BAR_LDS() asm volatile("s_waitcnt lgkmcnt(0)\n\ts_barrier" ::: "memory")

// gate-row scale: i,f,o -> -log2e (sigmoid w/ negated arg), g -> 2*log2e (tanh)
DEV float gscale(int q) { return (q == 2) ? K2 : -L2E; }

DEV float fexp2(float x) { return __builtin_amdgcn_exp2f(x); }   // v_exp_f32
DEV float frcp(float x)  { return __builtin_amdgcn_rcpf(x); }
DEV float rcp1p(float e) { return frcp(1.f + e); }

DEV unsigned short f2bf(float x) {
    __hip_bfloat16 h = __float2bfloat16(x);
    unsigned short u;
    __builtin_memcpy(&u, &h, 2);
    return u;
}
DEV float asf(unsigned int u) {
    float f;
    __builtin_memcpy(&f, &u, 4);
    return f;
}
DEV unsigned int pk2(float lo, float hi) {   // packed bf16 pair (RNE)
    __hip_bfloat162 b2 = __float22bfloat162_rn(make_float2(lo, hi));
    unsigned int u;
    __builtin_memcpy(&u, &b2, 4);
    return u;
}
DEV f32x4 unp4(unsigned int a, unsigned int b) {   // 4 bf16 -> 4 f32
    f32x4 v;
    v[0] = asf(a << 16); v[1] = asf(a & 0xffff0000u);
    v[2] = asf(b << 16); v[3] = asf(b & 0xffff0000u);
    return v;
}
DEV bf16x8 pack8(const float* f) {
    bf16x8 v;
#pragma unroll
    for (int e = 0; e < 8; ++e) v[e] = (short)f2bf(f[e]);
    return v;
}

// Fused LSTM cell update from scaled gates (i,f,g,o in acc regs 0..3):
// updates cst, returns h. 5 exp + 3 rcp.
DEV float cellup(const f32x4& acc, float& cst) {
    float Ai = fexp2(acc[0]);            // e^-i
    float Bg = fexp2(acc[2]);            // e^2g
    float sf = rcp1p(fexp2(acc[1]));     // sigmoid(f)
    float ig = (Bg - 1.f) * frcp((1.f + Ai) * (1.f + Bg));  // sig(i)*tanh(g)
    cst = __builtin_fmaf(sf, cst, ig);
    float Cc = fexp2(K2 * cst);          // e^2c
    float Do = fexp2(acc[3]);            // e^-o
    return (Cc - 1.f) * frcp((1.f + Do) * (1.f + Cc));      // sig(o)*tanh(c)
}

// ============================ bi-LSTM (MFMA) ================================
// Block = (prob, batch16); waves 0-3 = fwd chain, waves 4-7 = bwd chain.
// Acc reg r: q=r, cell hc = 16w+4lg+mt -> lane holds 4 consecutive cells.
struct BiArgs {
    const float* x[7];
    const float* Wih[2];
    const float* Whh[2];
    const float* bih[2];
    const float* bhh[2];
    unsigned short* outs_bf;   // [3][B][T][HH] bf16 (traj only)
    float* hid;                // [7][B][HH] fp32
};

__global__ __launch_bounds__(512) void k_bilstm_mfma(BiArgs a) {
    const int blk  = blockIdx.x;        // 56
    const int prob = blk >> 3;          // 0..6
    const int b0   = (blk & 7) * 16;
    const int tid  = threadIdx.x;
    const int dir  = tid >> 8;
    const int w    = (tid >> 6) & 3;    // wave-in-dir 0..3
    const int l    = tid & 63;
    const int lg   = l >> 4;
    const int lc   = l & 15;

    const float* Whh = a.Whh[dir];
    const float* Wih = a.Wih[dir];
    const float* bih = a.bih[dir];
    const float* bhh = a.bhh[dir];

    const float sw = gscale(lc & 3);
    bf16x8 wf[4][2];
#pragma unroll
    for (int mt = 0; mt < 4; ++mt) {
#pragma unroll
        for (int kh = 0; kh < 2; ++kh) {
            int orow = (lc & 3) * H2 + 16 * w + 4 * (lc >> 2) + mt;
            float tmp[8];
#pragma unroll
            for (int e = 0; e < 8; ++e)
                tmp[e] = Whh[(size_t)orow * H2 + 32 * kh + 8 * lg + e] * sw;
            wf[mt][kh] = pack8(tmp);
        }
    }
    float bia[4][4], wx0[4][4], wx1[4][4];
#pragma unroll
    for (int mt = 0; mt < 4; ++mt)
#pragma unroll
        for (int r = 0; r < 4; ++r) {
            int orow = r * H2 + 16 * w + 4 * lg + mt;
            float s = gscale(r);
            bia[mt][r] = (bih[orow] + bhh[orow]) * s;
            wx0[mt][r] = Wih[orow * 2 + 0] * s;
            wx1[mt][r] = Wih[orow * 2 + 1] * s;
        }

    __shared__ unsigned short Hb[2][2][8][16][8];   // [dir][buf][k>>3][batch][k&7]
    ((unsigned long long*)&Hb[tid >> 8][0][0][0][0])[tid & 255] = 0ULL;

    const bool isTraj = (prob >= 4);
    unsigned short* outp = a.outs_bf + (size_t)(isTraj ? (prob - 4) : 0) * BB * TT * HH;
    const float2* xg2 = (const float2*)a.x[prob];
    const int c = b0 + lc;

    float cst[4] = {0.f, 0.f, 0.f, 0.f};
    int cur = 0;
    float2 xrA = xg2[(size_t)c * TT + (dir ? TT - 1 : 0)];
    float2 xrB = xg2[(size_t)c * TT + (dir ? TT - 2 : 1)];
    __syncthreads();

#define BI_BODY(XR, T_)                                                          \
    {                                                                            \
        const int t = (T_);                                                      \
        f32x4 acc[4];                                                            \
        _Pragma("unroll")                                                        \
        for (int mt = 0; mt < 4; ++mt) {                                         \
            f32x4 v;                                                             \
            _Pragma("unroll")                                                    \
            for (int r = 0; r < 4; ++r)                                          \
                v[r] = __builtin_fmaf(wx0[mt][r], XR.x,                          \
                        __builtin_fmaf(wx1[mt][r], XR.y, bia[mt][r]));           \
            acc[mt] = v;                                                         \
        }                                                                        \
        {                                                                        \
            int tn = (t + 2 < TT) ? t + 2 : t;                                   \
            XR = xg2[(size_t)c * TT + (dir ? TT - 1 - tn : tn)];                 \
        }                                                                        \
        _Pragma("unroll")                                                        \
        for (int kh = 0; kh < 2; ++kh) {                                         \
            bf16x8 bfrag = *(const bf16x8*)&Hb[dir][cur][4 * kh + lg][lc][0];    \
            _Pragma("unroll")                                                    \
            for (int mt = 0; mt < 4; ++mt)                                       \
                acc[mt] = MFMA16(wf[mt][kh], bfrag, acc[mt]);                    \
        }                                                                        \
        const int nxt = cur ^ 1;                                                 \
        const int tcol = dir ? (TT - 1 - t) : t;                                 \
        float4 h4;                                                               \
        float* hp4 = &h4.x;                                                      \
        _Pragma("unroll")                                                        \
        for (int mt = 0; mt < 4; ++mt)                                           \
            hp4[mt] = cellup(acc[mt], cst[mt]);                                  \
        uint2 hpk = make_uint2(pk2(h4.x, h4.y), pk2(h4.z, h4.w));                \
        {                                                                        \
            int pp = 16 * w + 4 * lg;                                            \
            *(uint2*)&Hb[dir][nxt][pp >> 3][lc][pp & 7] = hpk;                   \
        }                                                                        \
        if (isTraj)                                                              \
            *(uint2*)&outp[((size_t)c * TT + tcol) * HH + dir * H2               \
                           + 16 * w + 4 * lg] = hpk;                             \
        if (t == TT - 1)                                                         \
            *(float4*)&a.hid[((size_t)prob * BB + c) * HH + dir * H2             \
                             + 16 * w + 4 * lg] = h4;                            \
        BAR_LDS();                                                               \
        cur = nxt;                                                               \
    }

    for (int t2 = 0; t2 < TT; t2 += 2) {
        BI_BODY(xrA, t2)
        BI_BODY(xrB, t2 + 1)
    }
#undef BI_BODY
}

// ---------- WxB[p][k] = mve_Wih[j][k]*gscale(q) bf16, p=4h+q, k<128 ----------
__global__ void k_wxB(const float* __restrict__ Wm, unsigned short* __restrict__ WxB) {
    int idx = blockIdx.x * 256 + threadIdx.x;   // 512*128
    int p = idx >> 7, k = idx & 127;
    int j = (p & 3) * HH + (p >> 2);
    WxB[idx] = f2bf(Wm[(size_t)j * (2 * HH) + k] * gscale(p & 3));
}

// ------------- hp: (hidden_l @ WihR.T + bias) scaled, permuted rows ---------
__global__ __launch_bounds__(256) void k_hp(const float* __restrict__ hidl,
                                            const float* __restrict__ Wih,
                                            const float* __restrict__ bih,
                                            const float* __restrict__ bhh,
                                            float* __restrict__ hp) {
    int traj = blockIdx.x, b = blockIdx.y;
    int j = threadIdx.x;
    __shared__ float hs[HH];
    if (j < HH) hs[j] = hidl[((size_t)traj * BB + b) * HH + j];
    __syncthreads();
    const float4* hs4 = (const float4*)hs;
#pragma unroll
    for (int rr = 0; rr < 2; ++rr) {
        int row = j + 256 * rr;
        float acc = bih[row] + bhh[row];
        const float4* w4 = (const float4*)(Wih + (size_t)row * (2 * HH) + HH);
#pragma unroll
        for (int k4 = 0; k4 < HH / 4; ++k4) {
            float4 wv = w4[k4], hv = hs4[k4];
            acc += wv.x * hv.x + wv.y * hv.y + wv.z * hv.z + wv.w * hv.w;
        }
        int p = 4 * (row & 127) + (row >> 7);
        hp[((size_t)traj * BB + b) * GM + p] = acc * gscale(row >> 7);
    }
}

// ===== xproj MFMA GEMM: xpb[traj][m][p] = outs_bf[m][:] . WxB[p][:] + hp =====
__global__ __launch_bounds__(256) void k_xproj_mfma(
    const unsigned short* __restrict__ outs_bf,  // [3][65536][128]
    const unsigned short* __restrict__ WxB,      // [512][128]
    const float* __restrict__ hp,                // [3][128][512]
    unsigned short* __restrict__ xpb) {          // [3][65536][512]
    const int mb   = blockIdx.x;   // 0..511
    const int pb   = blockIdx.y;   // 0..3
    const int traj = blockIdx.z;
    const int tid  = threadIdx.x;
    const int w = tid >> 6, l = tid & 63, lg = l >> 4, lc = l & 15;
    const int m0 = mb * 128;
    const int p0 = pb * 128;
    const int c  = m0 >> 9;

    __shared__ unsigned short Xs[128 * 128];   // xp tile 32KB (XOR-swizzled)
    __shared__ unsigned short Ps[128 * 128];   // WxB tile 32KB / C-tile reuse

    const uint4* xg4 = (const uint4*)(outs_bf + ((size_t)traj * (BB * TT) + m0) * HH);
    const uint4* pg4 = (const uint4*)(WxB + (size_t)p0 * HH);
#pragma unroll
    for (int i = 0; i < 8; ++i) {
        int j = i * 256 + tid;               // 16B chunk 0..2047
        int byte = j * 16;
        int row = byte >> 8;
        int sb = byte ^ ((row & 7) << 4);
        *(uint4*)((char*)Xs + sb) = xg4[j];
        *(uint4*)((char*)Ps + sb) = pg4[j];
    }
    __syncthreads();

    bf16x8 xfrag[2][4];
#pragma unroll
    for (int xt = 0; xt < 2; ++xt)
#pragma unroll
        for (int kh = 0; kh < 4; ++kh) {
            int row = 32 * w + 16 * xt + lc;
            int byte = row * 256 + 64 * kh + 16 * lg;
            xfrag[xt][kh] = *(const bf16x8*)((const char*)Xs + (byte ^ ((row & 7) << 4)));
        }
    f32x4 acc[8][2];
#pragma unroll
    for (int pt = 0; pt < 8; ++pt)
#pragma unroll
        for (int xt = 0; xt < 2; ++xt)
#pragma unroll
            for (int r = 0; r < 4; ++r) acc[pt][xt][r] = 0.f;

#pragma unroll
    for (int pt = 0; pt < 8; ++pt) {
        bf16x8 pf[4];
#pragma unroll
        for (int kh = 0; kh < 4; ++kh) {
            int row = 16 * pt + lc;
            int byte = row * 256 + 64 * kh + 16 * lg;
            pf[kh] = *(const bf16x8*)((const char*)Ps + (byte ^ ((row & 7) << 4)));
        }
#pragma unroll
        for (int kh = 0; kh < 4; ++kh)
#pragma unroll
            for (int xt = 0; xt < 2; ++xt)
                acc[pt][xt] = MFMA16(pf[kh], xfrag[xt][kh], acc[pt][xt]);
    }
    __syncthreads();   // all Ps frag reads done before C-tile overwrite

#pragma unroll
    for (int pt = 0; pt < 8; ++pt) {
        float4 hv = *(const float4*)&hp[(((size_t)traj * BB + c)) * GM + p0 + 16 * pt + 4 * lg];
#pragma unroll
        for (int xt = 0; xt < 2; ++xt) {
            int mloc = 32 * w + 16 * xt + lc;
            int byte = mloc * 256 + (16 * pt + 4 * lg) * 2;
            uint2 u = make_uint2(pk2(acc[pt][xt][0] + hv.x, acc[pt][xt][1] + hv.y),
                                 pk2(acc[pt][xt][2] + hv.z, acc[pt][xt][3] + hv.w));
            *(uint2*)((char*)Ps + (byte ^ ((mloc & 7) << 4))) = u;
        }
    }
    __syncthreads();

    unsigned short* Cg = xpb + ((size_t)traj * (BB * TT) + m0) * GM + p0;
#pragma unroll
    for (int i = 0; i < 8; ++i) {
        int j = i * 256 + tid;               // chunk
        int r = j >> 4;                      // m-row local
        int cb = (j & 15) * 16;              // byte within 256B row
        uint4 v = *(const uint4*)((const char*)Ps + ((r * 256 + cb) ^ ((r & 7) << 4)));
        *(uint4*)((char*)(Cg + (size_t)r * GM) + cb) = v;
    }
}

// ============================= mve scan (MFMA) ==============================
// 8 waves x 64 lanes; wave w owns cells [16w,16w+16) for 16 batch cols.
struct MveArgs {
    const unsigned short* xp;   // [3][B][T][512] bf16: scaled gates + hp folded
    const float* Whh;           // [512][128]
    float* mout;                // d_out+512: [3][B][T][HH] cell states
};

__global__ __launch_bounds__(512) void k_mve_mfma(MveArgs a) {
    const int blk  = blockIdx.x;   // 24
    const int traj = blk >> 3;
    const int b0   = (blk & 7) * 16;
    const int tid  = threadIdx.x;
    const int w    = tid >> 6;     // 0..7
    const int l    = tid & 63;
    const int lg   = l >> 4;
    const int lc   = l & 15;
    const int c    = b0 + lc;

    const float sw = gscale(lc & 3);
    bf16x8 wf[4][4];
#pragma unroll
    for (int mt = 0; mt < 4; ++mt) {
#pragma unroll
        for (int kh = 0; kh < 4; ++kh) {
            int orow = (lc & 3) * HH + 16 * w + 4 * (lc >> 2) + mt;
            float tmp[8];
#pragma unroll
            for (int e = 0; e < 8; ++e)
                tmp[e] = a.Whh[(size_t)orow * HH + 32 * kh + 8 * lg + e] * sw;
            wf[mt][kh] = pack8(tmp);
        }
    }

    __shared__ unsigned short Hb[2][16][16][8];   // 8KB
    ((unsigned long long*)Hb)[tid] = 0ULL;        // zero buf 0 exactly (4096B)

    const unsigned short* xrow = a.xp + (size_t)traj * BB * TT * GM
                               + (size_t)c * TT * GM + 64 * w + 16 * lg;
    float* mop = a.mout + (size_t)traj * BB * TT * HH
               + (size_t)c * TT * HH + 16 * w + 4 * lg;

    float cst[4] = {0.f, 0.f, 0.f, 0.f};
    int cur = 0;
    // 2-deep xp pipeline: A = even steps, B = odd steps
    uint4 xqA0 = *(const uint4*)xrow;
    uint4 xqA1 = *(const uint4*)(xrow + 8);
    uint4 xqB0 = *(const uint4*)(xrow + GM);
    uint4 xqB1 = *(const uint4*)(xrow + GM + 8);
    __syncthreads();

#define MVE_BODY(XQ0, XQ1, T_)                                                   \
    {                                                                            \
        const int t = (T_);                                                      \
        f32x4 acc[4];                                                            \
        acc[0] = unp4(XQ0.x, XQ0.y);                                             \
        acc[1] = unp4(XQ0.z, XQ0.w);                                             \
        acc[2] = unp4(XQ1.x, XQ1.y);                                             \
        acc[3] = unp4(XQ1.z, XQ1.w);                                             \
        {   /* re-issue this buffer's loads for t+2 */                           \
            const unsigned short* pf = xrow                                      \
                + (size_t)((t + 2 < TT) ? t + 2 : t) * GM;                       \
            XQ0 = *(const uint4*)pf;                                             \
            XQ1 = *(const uint4*)(pf + 8);                                       \
        }                                                                        \
        _Pragma("unroll")                                                        \
        for (int kh = 0; kh < 4; ++kh) {                                         \
            bf16x8 bfrag = *(const bf16x8*)&Hb[cur][4 * kh + lg][lc][0];         \
            _Pragma("unroll")                                                    \
            for (int mt = 0; mt < 4; ++mt)                                       \
                acc[mt] = MFMA16(wf[mt][kh], bfrag, acc[mt]);                    \
        }                                                                        \
        const int nxt = cur ^ 1;                                                 \
        f32x4 cs4;                                                               \
        float h8[4];                                                             \
        _Pragma("unroll")                                                        \
        for (int mt = 0; mt < 4; ++mt) {                                         \
            h8[mt] = cellup(acc[mt], cst[mt]);                                   \
            cs4[mt] = cst[mt];                                                   \
        }                                                                        \
        {                                                                        \
            int pp = 16 * w + 4 * lg;                                            \
            *(uint2*)&Hb[nxt][pp >> 3][lc][pp & 7] =                             \
                make_uint2(pk2(h8[0], h8[1]), pk2(h8[2], h8[3]));                \
        }                                                                        \
        /* CELL state: non-temporal (write-only stream; keep xp in L3) */        \
        __builtin_nontemporal_store(cs4, (f32x4*)(mop + (size_t)t * HH));        \
        BAR_LDS();                                                               \
        cur = nxt;                                                               \
    }

    for (int t2 = 0; t2 < TT; t2 += 2) {
        MVE_BODY(xqA0, xqA1, t2)
        MVE_BODY(xqB0, xqB1, t2 + 1)
    }
#undef MVE_BODY
}

// ----------------------------------------------------------------- sim ------
__global__ __launch_bounds__(128) void k_sim(const float* __restrict__ hid,
                                             const float* __restrict__ Wi, const float* __restrict__ bi,
                                             const float* __restrict__ Wc, const float* __restrict__ bc,
                                             const float* __restrict__ Wo, const float* __restrict__ bo,
                                             float* __restrict__ simv) {
    int which = blockIdx.x >> 7;
    int b = blockIdx.x & 127;
    int j = threadIdx.x;
    __shared__ float hs[HH];
    hs[j] = hid[((size_t)which * BB + b) * HH + j];
    __syncthreads();
    float ai = bi[j], ac = bc[j], ao = bo[j];
    const float4* wi4 = (const float4*)(Wi + (size_t)j * HH);
    const float4* wc4 = (const float4*)(Wc + (size_t)j * HH);
    const float4* wo4 = (const float4*)(Wo + (size_t)j * HH);
#pragma unroll
    for (int k4 = 0; k4 < HH / 4; ++k4) {
        float4 h = ((const float4*)hs)[k4];
        float4 vi = wi4[k4]; ai += vi.x*h.x + vi.y*h.y + vi.z*h.z + vi.w*h.w;
        float4 vc = wc4[k4]; ac += vc.x*h.x + vc.y*h.y + vc.z*h.z + vc.w*h.w;
        float4 vo = wo4[k4]; ao += vo.x*h.x + vo.y*h.y + vo.z*h.z + vo.w*h.w;
    }
    float Cv = (1.f / (1.f + __expf(-ai))) * tanhf(ac);
    float v = (1.f / (1.f + __expf(-ao))) * tanhf(Cv) + hs[j];
    simv[((size_t)which * BB + b) * HH + j] = v;
}

// ------------------------------------------------------------------ l2 ------
__global__ __launch_bounds__(64) void k_l2(const float* __restrict__ simv,
                                           float* __restrict__ out) {
    int p = blockIdx.x >> 7;
    int b = blockIdx.x & 127;
    int aw, cw;
    switch (p) {
        case 0: aw = 0; cw = 2; break;
        case 1: aw = 1; cw = 3; break;
        case 2: aw = 4; cw = 5; break;
        default: aw = 4; cw = 6; break;
    }
    int l = threadIdx.x;
    const float* va = simv + ((size_t)aw * BB + b) * HH;
    const float* vc = simv + ((size_t)cw * BB + b) * HH;
    float d0 = va[l] - vc[l];
    float d1 = va[l + 64] - vc[l + 64];
    float s = d0 * d0 + d1 * d1;
#pragma unroll
    for (int m = 32; m >= 1; m >>= 1) s += __shfl_xor(s, m, 64);
    if (l == 0) out[p * BB + b] = expf(-sqrtf(s));
}

// -------------------------------------------------------------- launcher ----
extern "C" void kernel_launch(void* const* d_in, const int* in_sizes, int n_in,
                              void* d_out_v, int out_size, void* d_ws, size_t ws_size,
                              hipStream_t stream) {
    const float* mWih  = (const float*)d_in[15];
    const float* mWhh  = (const float*)d_in[16];
    const float* mbih  = (const float*)d_in[17];
    const float* mbhh  = (const float*)d_in[18];
    const float* sWi   = (const float*)d_in[19];
    const float* sbi   = (const float*)d_in[20];
    const float* sWc   = (const float*)d_in[21];
    const float* sbc   = (const float*)d_in[22];
    const float* sWo   = (const float*)d_in[23];
    const float* sbo   = (const float*)d_in[24];

    constexpr size_t OUTSBF_LEN = (size_t)3 * BB * TT * HH;   // bf16
    constexpr size_t HID_LEN    = (size_t)7 * BB * HH;        // f32
    constexpr size_t WXB_LEN    = (size_t)GM * HH;            // bf16
    constexpr size_t SIMV_LEN   = HID_LEN;                    // f32
    constexpr size_t HP_LEN     = (size_t)3 * BB * GM;        // f32
    constexpr size_t XP_LEN     = (size_t)3 * BB * TT * GM;   // bf16

    char* ws = (char*)d_ws;
    unsigned short* outs_bf = (unsigned short*)ws;                 ws += OUTSBF_LEN * 2;
    float*          hid     = (float*)ws;                          ws += HID_LEN * 4;
    unsigned short* WxB     = (unsigned short*)ws;                 ws += WXB_LEN * 2;
    float*          simv    = (float*)ws;                          ws += SIMV_LEN * 4;
    float*          hp      = (float*)ws;                          ws += HP_LEN * 4;
    unsigned short* xpb     = (unsigned short*)ws;                 ws += XP_LEN * 2;

    float* dout = (float*)d_out_v;
    float* mout = dout + 512;

    BiArgs ba;
    for (int i = 0; i < 7; ++i) ba.x[i] = (const float*)d_in[i];
    ba.Wih[0] = (const float*)d_in[7];  ba.Whh[0] = (const float*)d_in[8];
    ba.bih[0] = (const float*)d_in[9];  ba.bhh[0] = (const float*)d_in[10];
    ba.Wih[1] = (const float*)d_in[11]; ba.Whh[1] = (const float*)d_in[12];
    ba.bih[1] = (const float*)d_in[13]; ba.bhh[1] = (const float*)d_in[14];
    ba.outs_bf = outs_bf; ba.hid = hid;

    k_wxB<<<256, 256, 0, stream>>>(mWih, WxB);
    k_bilstm_mfma<<<56, 512, 0, stream>>>(ba);
    k_hp<<<dim3(3, BB), 256, 0, stream>>>(hid + (size_t)4 * BB * HH, mWih, mbih, mbhh, hp);

    dim3 gx(BB * TT / 128, GM / 128, 3);
    k_xproj_mfma<<<gx, 256, 0, stream>>>(outs_bf, WxB, hp, xpb);

    MveArgs ma;
    ma.xp = xpb; ma.Whh = mWhh; ma.mout = mout;
    k_mve_mfma<<<24, 512, 0, stream>>>(ma);

    k_sim<<<7 * BB, 128, 0, stream>>>(hid, sWi, sbi, sWc, sbc, sWo, sbo, simv);
    k_l2<<<4 * BB, 64, 0, stream>>>(simv, dout);
}